// Round 8
// baseline (145.124 us; speedup 1.0000x reference)
//
#include <hip/hip_runtime.h>
#include <math.h>

typedef float f32x16 __attribute__((ext_vector_type(16)));
typedef short bf16x8 __attribute__((ext_vector_type(8)));
typedef short bf16x4 __attribute__((ext_vector_type(4)));
typedef unsigned short u16;
typedef unsigned int u32;

#define MFMA32(a, b, c) __builtin_amdgcn_mfma_f32_32x32x16_bf16(a, b, c, 0, 0, 0)

__device__ __forceinline__ u16 f2bf(float x) {
    u32 u = __float_as_uint(x);
    u += 0x7FFFu + ((u >> 16) & 1u);
    return (u16)(u >> 16);
}
__device__ __forceinline__ float bf2f(u16 h) {
    return __uint_as_float(((u32)h) << 16);
}

// ---------------------------------------------------------------------------
// prep v7b: split bf16 hi/lo planes, V hi-only. (v7 + fixed vst copy-out)
//   waves 0/1: vector features (q copy*SC + V; k = metric*G@u, G=Wq^T Wk)
//   waves 2/3: scalar projections via MFMA GEMM
// Outputs: qh/ql/kh/kl u16 [tok][128]; vth [b][dv][1024].
// ---------------------------------------------------------------------------
__global__ __launch_bounds__(256) void prep_kernel(
    const float* __restrict__ vectors, const float* __restrict__ scalars,
    const float* __restrict__ Wq, const float* __restrict__ Wq_s, const float* __restrict__ bq_s,
    const float* __restrict__ Wk, const float* __restrict__ Wk_s, const float* __restrict__ bk_s,
    const float* __restrict__ Wv,
    u16* __restrict__ qh, u16* __restrict__ ql,
    u16* __restrict__ kh, u16* __restrict__ kl,
    u16* __restrict__ vth)
{
    __shared__ float vl[64 * 68];    // normalized vectors [tok][64]
    __shared__ u16 vst[64 * 66];     // v staging [dv][tok]
    __shared__ float wls[1024];      // Wq (512) | Wk (512)

    const int t = threadIdx.x;
    const int lane = t & 63;
    const int w = t >> 6;
    const int b = blockIdx.x >> 4;
    const int n0 = (blockIdx.x & 15) << 6;
    const long tok0 = (long)b * 1024 + n0;
    const float SC = 0.07216878364870323f;   // 1/sqrt(192)

    const float4* vin = (const float4*)(vectors + tok0 * 64);
#pragma unroll
    for (int r = 0; r < 4; ++r) {
        int i4 = t + (r << 8);
        int tok = i4 >> 4, c4 = (i4 & 15) << 2;
        *(float4*)&vl[tok * 68 + c4] = vin[i4];
    }
    for (int i = t; i < 1024; i += 256) wls[i] = (i < 512) ? Wq[i] : Wk[i - 512];
    __syncthreads();

#pragma unroll
    for (int r = 0; r < 4; ++r) {
        int gi = t + (r << 8);
        float* p = &vl[(gi >> 4) * 68 + ((gi & 15) << 2)];
        float x0 = p[0], x1 = p[1], x2 = p[2], x3 = p[3];
        float nrm = x0 * x0 - x1 * x1 - x2 * x2 - x3 * x3;
        float inv = 1.0f / sqrtf(fmaxf(fabsf(nrm), 1e-5f));
        p[0] = x0 * inv; p[1] = x1 * inv; p[2] = x2 * inv; p[3] = x3 * inv;
    }
    __syncthreads();

    if (w == 0) {
        float wrv[16];
#pragma unroll
        for (int j = 0; j < 16; ++j) wrv[j] = expf(Wv[(lane >> 2) * 16 + j]);
        const int vc = lane & 3;
        for (int tok = 0; tok < 64; ++tok) {
            float q = vl[tok * 68 + lane] * SC;
            u16 h = f2bf(q);
            long o_ = (tok0 + tok) * 128 + lane;
            qh[o_] = h; ql[o_] = f2bf(q - bf2f(h));
            const float* p0 = &vl[tok * 68 + vc];
            float a0 = 0.f, a1 = 0.f, a2 = 0.f, a3 = 0.f;
#pragma unroll
            for (int j = 0; j < 16; j += 4) {
                a0 = fmaf(wrv[j],     p0[j * 4],       a0);
                a1 = fmaf(wrv[j + 1], p0[(j + 1) * 4], a1);
                a2 = fmaf(wrv[j + 2], p0[(j + 2) * 4], a2);
                a3 = fmaf(wrv[j + 3], p0[(j + 3) * 4], a3);
            }
            vst[lane * 66 + tok] = f2bf((a0 + a1) + (a2 + a3));
        }
    } else if (w == 1) {
        const int i_ = lane >> 2, c = lane & 3;
        const float mc = (c == 0) ? 1.f : -1.f;
        float wqc[32];
#pragma unroll
        for (int f = 0; f < 32; ++f) wqc[f] = wls[f * 16 + i_];
        float gr[16];
#pragma unroll
        for (int jp = 0; jp < 16; ++jp) {
            float a0 = 0.f, a1 = 0.f;
#pragma unroll
            for (int f = 0; f < 32; f += 2) {
                a0 = fmaf(wqc[f],     wls[512 + f * 16 + jp],       a0);
                a1 = fmaf(wqc[f + 1], wls[512 + (f + 1) * 16 + jp], a1);
            }
            gr[jp] = (a0 + a1) * mc;
        }
        for (int tok = 0; tok < 64; ++tok) {
            const float* p0 = &vl[tok * 68 + c];
            float a0 = 0.f, a1 = 0.f, a2 = 0.f, a3 = 0.f;
#pragma unroll
            for (int jp = 0; jp < 16; jp += 4) {
                a0 = fmaf(gr[jp],     p0[jp * 4],       a0);
                a1 = fmaf(gr[jp + 1], p0[(jp + 1) * 4], a1);
                a2 = fmaf(gr[jp + 2], p0[(jp + 2) * 4], a2);
                a3 = fmaf(gr[jp + 3], p0[(jp + 3) * 4], a3);
            }
            float a = (a0 + a1) + (a2 + a3);
            u16 h = f2bf(a);
            long o_ = (tok0 + tok) * 128 + lane;
            kh[o_] = h; kl[o_] = f2bf(a - bf2f(h));
        }
    } else {
        // scalar projections via MFMA
        const int tokbase = (w == 2) ? 0 : 32;
        const int l31 = lane & 31, g = lane >> 5;

        bf16x8 Ah[4], Al[4];
        const float* xrow = scalars + (tok0 + tokbase + l31) * 64 + g * 8;
#pragma unroll
        for (int kk = 0; kk < 4; ++kk) {
            float4 x0 = *(const float4*)(xrow + kk * 16);
            float4 x1 = *(const float4*)(xrow + kk * 16 + 4);
            float xs[8] = {x0.x, x0.y, x0.z, x0.w, x1.x, x1.y, x1.z, x1.w};
#pragma unroll
            for (int e = 0; e < 8; ++e) {
                u16 h = f2bf(xs[e]);
                Ah[kk][e] = (short)h;
                Al[kk][e] = (short)f2bf(xs[e] - bf2f(h));
            }
        }

#pragma unroll
        for (int ft = 0; ft < 4; ++ft) {
            const int isq = (ft < 2);
            const int fs = ((ft & 1) << 5) + l31;
            const float* wrow = (isq ? Wq_s : Wk_s) + fs * 64 + g * 8;
            f32x16 acc;
#pragma unroll
            for (int r = 0; r < 16; ++r) acc[r] = 0.f;
#pragma unroll
            for (int kk = 0; kk < 4; ++kk) {
                float4 w0_ = *(const float4*)(wrow + kk * 16);
                float4 w1_ = *(const float4*)(wrow + kk * 16 + 4);
                float ws_[8] = {w0_.x, w0_.y, w0_.z, w0_.w, w1_.x, w1_.y, w1_.z, w1_.w};
                bf16x8 Bh, Bl;
#pragma unroll
                for (int e = 0; e < 8; ++e) {
                    u16 h = f2bf(ws_[e]);
                    Bh[e] = (short)h;
                    Bl[e] = (short)f2bf(ws_[e] - bf2f(h));
                }
                acc = MFMA32(Ah[kk], Bh, acc);
                acc = MFMA32(Ah[kk], Bl, acc);
                acc = MFMA32(Al[kk], Bh, acc);
            }
            const float bias = (isq ? bq_s : bk_s)[fs];
            const float sc = isq ? SC : 1.f;
            u16* oh = isq ? qh : kh;
            u16* ol = isq ? ql : kl;
#pragma unroll
            for (int reg = 0; reg < 16; ++reg) {
                int trow = (reg & 3) + 8 * (reg >> 2) + 4 * g;
                float val = (acc[reg] + bias) * sc;
                u16 h = f2bf(val);
                long o_ = (tok0 + tokbase + trow) * 128 + 64 + fs;
                oh[o_] = h; ol[o_] = f2bf(val - bf2f(h));
            }
        }
    }
    __syncthreads();

    // coalesced v copy-out (hi only): 2048 iters x 2 tokens = 64 dv x 64 tok
#pragma unroll
    for (int r = 0; r < 8; ++r) {
        int i = t + (r << 8);            // 0..2047
        int dv = i >> 5;                 // 0..63
        int tp = (i & 31) << 1;          // 0,2,..,62
        u16 p0 = vst[dv * 66 + tp];
        u16 p1 = vst[dv * 66 + tp + 1];
        long o = ((long)b * 64 + dv) * 1024 + n0 + tp;
        *(u32*)(vth + o) = (u32)p0 | ((u32)p1 << 16);
    }
}

// ---------------------------------------------------------------------------
// MFMA flash attention v7: 2 waves x 64 q = 128 q/block, KT=32 double-buffered.
// K LDS pitch 128 u16 with 16B-unit XOR swizzle (unit ^= row&15) -> conflict-
// free b128 reads. Each K fragment feeds 2 Q-register sets (6 MFMA / fetch).
// PV uses V hi-plane only. 1 wave/SIMD (high VGPR).
// ---------------------------------------------------------------------------
__global__ __launch_bounds__(128, 1) void attn_kernel(
    const u16* __restrict__ qh, const u16* __restrict__ ql,
    const u16* __restrict__ kh, const u16* __restrict__ kl,
    const u16* __restrict__ vth, float* __restrict__ out)
{
    __shared__ u16 KH[2 * 32 * 128];
    __shared__ u16 KL[2 * 32 * 128];
    __shared__ u16 VH[2 * 64 * 40];

    const int t = threadIdx.x;
    const int lane = t & 63;
    const int w = t >> 6;            // 0..1
    const int l31 = lane & 31, g = lane >> 5;

    const int bid = blockIdx.x;
    const int b = ((bid & 7) << 3) + (bid >> 6);
    const int qt = (bid >> 3) & 7;

    const long qtokA = (long)b * 1024 + qt * 128 + w * 64 + l31;
    const long qtokB = qtokA + 32;

    // ---- Q fragments, 2 sets ----
    bf16x8 QhA[8], QlA[8], QhB[8], QlB[8];
    {
        const u16* pah = qh + qtokA * 128 + g * 8;
        const u16* pal = ql + qtokA * 128 + g * 8;
        const u16* pbh = qh + qtokB * 128 + g * 8;
        const u16* pbl = ql + qtokB * 128 + g * 8;
#pragma unroll
        for (int c = 0; c < 8; ++c) {
            QhA[c] = *(const bf16x8*)(pah + c * 16);
            QlA[c] = *(const bf16x8*)(pal + c * 16);
            QhB[c] = *(const bf16x8*)(pbh + c * 16);
            QlB[c] = *(const bf16x8*)(pbl + c * 16);
        }
    }

    // ---- staging maps (128 threads) ----
    const int srow = t >> 2, sq4 = t & 3;
    const u16* khg = kh + ((long)b * 1024 + srow) * 128 + sq4 * 32;
    const u16* klg = kl + ((long)b * 1024 + srow) * 128 + sq4 * 32;
    const int sdv = t >> 1, shalf = t & 1;
    const u16* vhg = vth + ((long)b * 64 + sdv) * 1024 + shalf * 16;

    int kdst0 = srow * 128 + (((sq4 << 2) + 0) ^ (srow & 15)) * 8;
    int kdst1 = srow * 128 + (((sq4 << 2) + 1) ^ (srow & 15)) * 8;
    int kdst2 = srow * 128 + (((sq4 << 2) + 2) ^ (srow & 15)) * 8;
    int kdst3 = srow * 128 + (((sq4 << 2) + 3) ^ (srow & 15)) * 8;
    u16* vdst = VH + sdv * 40 + shalf * 16;

    int4 rk0, rk1, rk2, rk3, rl0, rl1, rl2, rl3, rv0, rv1;

#define LOADT(kt) do { \
        const u16* p1 = khg + (long)(kt) * 128; \
        rk0 = *(const int4*)(p1);      rk1 = *(const int4*)(p1 + 8); \
        rk2 = *(const int4*)(p1 + 16); rk3 = *(const int4*)(p1 + 24); \
        const u16* p2 = klg + (long)(kt) * 128; \
        rl0 = *(const int4*)(p2);      rl1 = *(const int4*)(p2 + 8); \
        rl2 = *(const int4*)(p2 + 16); rl3 = *(const int4*)(p2 + 24); \
        rv0 = *(const int4*)(vhg + (kt)); \
        rv1 = *(const int4*)(vhg + (kt) + 8); \
    } while (0)

#define WRITET(buf) do { \
        u16* d1 = KH + (buf) * 4096; \
        *(int4*)(d1 + kdst0) = rk0; *(int4*)(d1 + kdst1) = rk1; \
        *(int4*)(d1 + kdst2) = rk2; *(int4*)(d1 + kdst3) = rk3; \
        u16* d2 = KL + (buf) * 4096; \
        *(int4*)(d2 + kdst0) = rl0; *(int4*)(d2 + kdst1) = rl1; \
        *(int4*)(d2 + kdst2) = rl2; *(int4*)(d2 + kdst3) = rl3; \
        *(int4*)(vdst + (buf) * 2560) = rv0; \
        *(int4*)(vdst + (buf) * 2560 + 8) = rv1; \
    } while (0)

    f32x16 oA0, oA1, oB0, oB1;
#pragma unroll
    for (int r = 0; r < 16; ++r) { oA0[r] = 0.f; oA1[r] = 0.f; oB0[r] = 0.f; oB1[r] = 0.f; }
    float mA = -1e30f, lA = 0.f, mB = -1e30f, lB = 0.f;

    LOADT(0);
    WRITET(0);
    __syncthreads();

    for (int it = 0; it < 32; ++it) {
        const int cb = it & 1;
        if (it < 31) LOADT((it + 1) * 32);

        // ---- QK^T: shared K fragments feed both Q sets ----
        f32x16 sA0, sB0, sA1, sB1;
#pragma unroll
        for (int r = 0; r < 16; ++r) { sA0[r] = 0.f; sB0[r] = 0.f; sA1[r] = 0.f; sB1[r] = 0.f; }
        const u16* kbh = KH + cb * 4096 + l31 * 128;
        const u16* kbl = KL + cb * 4096 + l31 * 128;
        const int rs = l31 & 15;
        __builtin_amdgcn_s_setprio(1);
#pragma unroll
        for (int c = 0; c < 8; ++c) {
            const int off = ((g + 2 * c) ^ rs) * 8;
            bf16x8 fh = *(const bf16x8*)(kbh + off);
            bf16x8 fl = *(const bf16x8*)(kbl + off);
            sA0 = MFMA32(fh, QhA[c], sA0);
            sA1 = MFMA32(fh, QhB[c], sA1);
            sB0 = MFMA32(fh, QlA[c], sB0);
            sB1 = MFMA32(fh, QlB[c], sB1);
            sB0 = MFMA32(fl, QhA[c], sB0);
            sB1 = MFMA32(fl, QhB[c], sB1);
        }
        __builtin_amdgcn_s_setprio(0);

        // ---- softmax set A ----
        bf16x8 phA0, phA1, phB0, phB1;
        {
            float s0[16];
#pragma unroll
            for (int r = 0; r < 16; ++r) s0[r] = sA0[r] + sB0[r];
            float mt = s0[0];
#pragma unroll
            for (int r = 1; r < 16; ++r) mt = fmaxf(mt, s0[r]);
            mt = fmaxf(mt, __shfl_xor(mt, 32));
            if (!__all(mt - mA <= 8.f)) {
                float mn = fmaxf(mA, mt);
                float corr = __expf(mA - mn);
                lA *= corr;
#pragma unroll
                for (int r = 0; r < 16; ++r) { oA0[r] *= corr; oA1[r] *= corr; }
                mA = mn;
            }
            float ps = 0.f;
#pragma unroll
            for (int r = 0; r < 16; ++r) { s0[r] = __expf(s0[r] - mA); ps += s0[r]; }
            ps += __shfl_xor(ps, 32);
            lA += ps;
#pragma unroll
            for (int e = 0; e < 8; ++e) {
                phA0[e] = (short)f2bf(s0[e]);
                phA1[e] = (short)f2bf(s0[8 + e]);
            }
        }
        // ---- softmax set B ----
        {
            float s1[16];
#pragma unroll
            for (int r = 0; r < 16; ++r) s1[r] = sA1[r] + sB1[r];
            float mt = s1[0];
#pragma unroll
            for (int r = 1; r < 16; ++r) mt = fmaxf(mt, s1[r]);
            mt = fmaxf(mt, __shfl_xor(mt, 32));
            if (!__all(mt - mB <= 8.f)) {
                float mn = fmaxf(mB, mt);
                float corr = __expf(mB - mn);
                lB *= corr;
#pragma unroll
                for (int r = 0; r < 16; ++r) { oB0[r] *= corr; oB1[r] *= corr; }
                mB = mn;
            }
            float ps = 0.f;
#pragma unroll
            for (int r = 0; r < 16; ++r) { s1[r] = __expf(s1[r] - mB); ps += s1[r]; }
            ps += __shfl_xor(ps, 32);
            lB += ps;
#pragma unroll
            for (int e = 0; e < 8; ++e) {
                phB0[e] = (short)f2bf(s1[e]);
                phB1[e] = (short)f2bf(s1[8 + e]);
            }
        }

        // ---- V fragments (hi only), shared across both sets ----
        const u16* vb = VH + cb * 2560;
        bf16x8 v00, v01, v10, v11;
        {
            const u16* p00 = vb + l31 * 40 + g * 4;
            const u16* p10 = vb + (32 + l31) * 40 + g * 4;
            bf16x4 a0 = *(const bf16x4*)(p00);      bf16x4 a1 = *(const bf16x4*)(p00 + 8);
            bf16x4 b0 = *(const bf16x4*)(p00 + 16); bf16x4 b1 = *(const bf16x4*)(p00 + 24);
            bf16x4 c0 = *(const bf16x4*)(p10);      bf16x4 c1 = *(const bf16x4*)(p10 + 8);
            bf16x4 d0 = *(const bf16x4*)(p10 + 16); bf16x4 d1 = *(const bf16x4*)(p10 + 24);
            v00 = __builtin_shufflevector(a0, a1, 0, 1, 2, 3, 4, 5, 6, 7);
            v01 = __builtin_shufflevector(b0, b1, 0, 1, 2, 3, 4, 5, 6, 7);
            v10 = __builtin_shufflevector(c0, c1, 0, 1, 2, 3, 4, 5, 6, 7);
            v11 = __builtin_shufflevector(d0, d1, 0, 1, 2, 3, 4, 5, 6, 7);
        }

        __builtin_amdgcn_s_setprio(1);
        oA0 = MFMA32(v00, phA0, oA0);
        oA0 = MFMA32(v01, phA1, oA0);
        oA1 = MFMA32(v10, phA0, oA1);
        oA1 = MFMA32(v11, phA1, oA1);
        oB0 = MFMA32(v00, phB0, oB0);
        oB0 = MFMA32(v01, phB1, oB0);
        oB1 = MFMA32(v10, phB0, oB1);
        oB1 = MFMA32(v11, phB1, oB1);
        __builtin_amdgcn_s_setprio(0);

        if (it < 31) WRITET(cb ^ 1);
        __syncthreads();
    }

    // ---- epilogue ----
    float invA = 1.0f / lA, invB = 1.0f / lB;
    float* opA = out + qtokA * 64;
    float* opB = out + qtokB * 64;
#pragma unroll
    for (int sg = 0; sg < 4; ++sg) {
        *(float4*)(opA + sg * 8 + g * 4) = make_float4(
            oA0[4*sg+0]*invA, oA0[4*sg+1]*invA, oA0[4*sg+2]*invA, oA0[4*sg+3]*invA);
        *(float4*)(opA + 32 + sg * 8 + g * 4) = make_float4(
            oA1[4*sg+0]*invA, oA1[4*sg+1]*invA, oA1[4*sg+2]*invA, oA1[4*sg+3]*invA);
        *(float4*)(opB + sg * 8 + g * 4) = make_float4(
            oB0[4*sg+0]*invB, oB0[4*sg+1]*invB, oB0[4*sg+2]*invB, oB0[4*sg+3]*invB);
        *(float4*)(opB + 32 + sg * 8 + g * 4) = make_float4(
            oB1[4*sg+0]*invB, oB1[4*sg+1]*invB, oB1[4*sg+2]*invB, oB1[4*sg+3]*invB);
    }
#undef LOADT
#undef WRITET
}

extern "C" void kernel_launch(void* const* d_in, const int* in_sizes, int n_in,
                              void* d_out, int out_size, void* d_ws, size_t ws_size,
                              hipStream_t stream) {
    const float* vectors = (const float*)d_in[0];
    const float* scalars = (const float*)d_in[1];
    const float* Wq   = (const float*)d_in[2];
    const float* Wq_s = (const float*)d_in[3];
    const float* bq_s = (const float*)d_in[4];
    const float* Wk   = (const float*)d_in[5];
    const float* Wk_s = (const float*)d_in[6];
    const float* bk_s = (const float*)d_in[7];
    const float* Wv   = (const float*)d_in[8];
    float* o = (float*)d_out;

    u16* qh  = (u16*)d_ws;                 // 64*1024*128 each
    u16* ql  = qh + 8388608;
    u16* kh  = ql + 8388608;
    u16* kl  = kh + 8388608;
    u16* vth = kl + 8388608;               // 64*64*1024

    prep_kernel<<<1024, 256, 0, stream>>>(vectors, scalars, Wq, Wq_s, bq_s,
                                          Wk, Wk_s, bk_s, Wv,
                                          qh, ql, kh, kl, vth);
    attn_kernel<<<512, 128, 0, stream>>>(qh, ql, kh, kl, vth, o);
}